// Round 1
// baseline (468.749 us; speedup 1.0000x reference)
//
#include <hip/hip_runtime.h>

constexpr int Dd = 128, Hh = 128, Ww = 128;
constexpr int B = 2, L = 8;
constexpr int S_SP = Dd * Hh * Ww;              // 2097152 spatial voxels
constexpr float CLAMP_MIN = 0.071f;
constexpr float EPS = 1e-5f;

// ---------------- Kernel 1: softmax over L + clamp, write to ws ----------------
// One thread handles 4 consecutive voxels (float4) across all 8 labels.
__global__ __launch_bounds__(256) void softmax_clamp_kernel(
    const float* __restrict__ pred, float* __restrict__ ps) {
  const int S4 = S_SP / 4;
  int g = blockIdx.x * blockDim.x + threadIdx.x;   // over B * S4
  int b = g / S4;
  int s4 = g - b * S4;
  const float4* in = (const float4*)(pred + (size_t)b * L * S_SP) + s4;
  float4* out = (float4*)(ps + (size_t)b * L * S_SP) + s4;

  float v[L][4];
#pragma unroll
  for (int l = 0; l < L; ++l) {
    float4 t = in[(size_t)l * S4];
    v[l][0] = t.x; v[l][1] = t.y; v[l][2] = t.z; v[l][3] = t.w;
  }
#pragma unroll
  for (int c = 0; c < 4; ++c) {
    float m = v[0][c];
#pragma unroll
    for (int l = 1; l < L; ++l) m = fmaxf(m, v[l][c]);
    float s = 0.f;
#pragma unroll
    for (int l = 0; l < L; ++l) { v[l][c] = expf(v[l][c] - m); s += v[l][c]; }
    float inv = 1.f / s;
#pragma unroll
    for (int l = 0; l < L; ++l) v[l][c] = fmaxf(v[l][c] * inv, CLAMP_MIN);
  }
#pragma unroll
  for (int l = 0; l < L; ++l) {
    float4 t;
    t.x = v[l][0]; t.y = v[l][1]; t.z = v[l][2]; t.w = v[l][3];
    out[(size_t)l * S4] = t;
  }
}

// ------------- Kernel 2: 27-pt stencil w/ reflection + fused dice partials -------------
// One block per (b*L + l, d) plane; 256 threads loop over 128x128 voxels.
__global__ __launch_bounds__(256) void stencil_reduce_kernel(
    const float* __restrict__ ps, const float* __restrict__ pred,
    const float* __restrict__ tgt, float* __restrict__ acc /* 16 pairs */) {
  int blk = blockIdx.x;          // bl*128 + d
  int d = blk & 127;
  int bl = blk >> 7;             // b*L + l in [0,16)
  const size_t slice = (size_t)bl * S_SP;
  const float* P = ps + slice;

  int dm = (d == 0) ? 1 : d - 1;
  int dp = (d == Dd - 1) ? Dd - 2 : d + 1;
  const float* pl0 = P + (size_t)dm * Hh * Ww;
  const float* pl1 = P + (size_t)d  * Hh * Ww;
  const float* pl2 = P + (size_t)dp * Hh * Ww;

  float top = 0.f, bot = 0.f;

  for (int it = 0; it < (Hh * Ww) / 256; ++it) {
    int idx = it * 256 + threadIdx.x;   // 0..16383 in plane
    int h = idx >> 7;
    int w = idx & 127;
    int hm = (h == 0) ? 1 : h - 1;
    int hp = (h == Hh - 1) ? Hh - 2 : h + 1;
    int wm = (w == 0) ? 1 : w - 1;
    int wp = (w == Ww - 1) ? Ww - 2 : w + 1;

    float s = 0.f;
    const float* pls[3] = {pl0, pl1, pl2};
#pragma unroll
    for (int z = 0; z < 3; ++z) {
      const float* pb = pls[z];
      int hs[3] = {hm, h, hp};
#pragma unroll
      for (int y = 0; y < 3; ++y) {
        const float* row = pb + hs[y] * Ww;
        s += row[wm] + row[w] + row[wp];
      }
    }
    float c = pl1[h * Ww + w];
    float bt = fabsf(27.f * c - s);
    float bw = 0.5f / (bt + 0.5f);

    size_t off = slice + (size_t)d * Hh * Ww + idx;
    float p = pred[off];
    float t = tgt[off];
    top += t * p * bw;
    bot += (t + p) * bw;
  }

  // wave reduce (64 lanes) then cross-wave via LDS
#pragma unroll
  for (int o = 32; o > 0; o >>= 1) {
    top += __shfl_down(top, o, 64);
    bot += __shfl_down(bot, o, 64);
  }
  __shared__ float st[4], sb[4];
  int lane = threadIdx.x & 63;
  int wv = threadIdx.x >> 6;
  if (lane == 0) { st[wv] = top; sb[wv] = bot; }
  __syncthreads();
  if (threadIdx.x == 0) {
    float T = st[0] + st[1] + st[2] + st[3];
    float Bo = sb[0] + sb[1] + sb[2] + sb[3];
    atomicAdd(&acc[bl * 2 + 0], T);
    atomicAdd(&acc[bl * 2 + 1], Bo);
  }
}

// ---------------- Kernel 3: 16 ratios -> scalar ----------------
__global__ void finalize_kernel(const float* __restrict__ acc, float* __restrict__ out) {
  int t = threadIdx.x;
  float r = 0.f;
  if (t < B * L) {
    float topv = 2.f * acc[t * 2 + 0];
    float botv = fmaxf(acc[t * 2 + 1], EPS);
    r = topv / botv;
  }
#pragma unroll
  for (int o = 32; o > 0; o >>= 1) r += __shfl_down(r, o, 64);
  if (t == 0) out[0] = -r / (float)(B * L);
}

extern "C" void kernel_launch(void* const* d_in, const int* in_sizes, int n_in,
                              void* d_out, int out_size, void* d_ws, size_t ws_size,
                              hipStream_t stream) {
  const float* pred = (const float*)d_in[0];
  const float* tgt  = (const float*)d_in[1];
  float* ps  = (float*)d_ws;                                   // 2*8*128^3 fp32 = 134 MB
  float* acc = (float*)((char*)d_ws + (size_t)B * L * S_SP * sizeof(float));

  hipMemsetAsync(acc, 0, 2 * B * L * sizeof(float), stream);

  int g1 = (B * (S_SP / 4)) / 256;   // 4096 blocks
  softmax_clamp_kernel<<<g1, 256, 0, stream>>>(pred, ps);

  stencil_reduce_kernel<<<B * L * Dd, 256, 0, stream>>>(ps, pred, tgt, acc);

  finalize_kernel<<<1, 64, 0, stream>>>(acc, (float*)d_out);
}

// Round 2
// 345.631 us; speedup vs baseline: 1.3562x; 1.3562x over previous
//
#include <hip/hip_runtime.h>

constexpr int Dd = 128, Hh = 128, Ww = 128;
constexpr int B_ = 2, L_ = 8;
constexpr int S_SP = Dd * Hh * Ww;          // 2097152
constexpr float CLAMP_MIN = 0.071f;
constexpr float EPS = 1e-5f;

constexpr int TIL = 16;                     // hw tile
constexpr int HALO = TIL + 2;               // 18
constexpr int DCH = 16;                     // d planes per block
constexpr int NPOS = HALO * HALO;           // 324
constexpr int BLK_PER_B = (Dd / DCH) * (Hh / TIL) * (Ww / TIL);  // 512
constexpr int NBLK = B_ * BLK_PER_B;        // 1024

__device__ __forceinline__ int refl(int x, int n) {
  return x < 0 ? 1 : (x >= n ? n - 2 : x);
}

// One block: (b, d-chunk, 16x16 hw tile), all 8 labels.
// Per plane: halo softmax -> LDS [pos][8]; rolling 3x3 sums in regs over d.
__global__ __launch_bounds__(256) void fused_kernel(
    const float* __restrict__ pred, const float* __restrict__ tgt,
    float* __restrict__ partial) {
  __shared__ float sps[NPOS][L_];     // 324*8*4 = 10368 B
  __shared__ float red[4][16];

  int blk = blockIdx.x;
  int tw = blk & 7, th = (blk >> 3) & 7, dc = (blk >> 6) & 7, b = blk >> 9;
  int h0 = th * TIL, w0 = tw * TIL, d0 = dc * DCH;
  int tid = threadIdx.x;
  int hl = tid >> 4, wl = tid & 15;
  const float* predb = pred + (size_t)b * L_ * S_SP;

  float s2m[L_], s2c[L_], s2n[L_], ctrc[L_], ctrn[L_];
  float atop[L_], abot[L_];
#pragma unroll
  for (int l = 0; l < L_; ++l) { atop[l] = 0.f; abot[l] = 0.f; }

  for (int pp = -1; pp <= DCH; ++pp) {
    int pd = d0 + pp;
    int rpd = pd < 0 ? 1 : (pd >= Dd ? Dd - 2 : pd);
    __syncthreads();   // everyone done reading previous plane
    // ---- load halo positions, softmax+clamp, write to LDS ----
    for (int pos = tid; pos < NPOS; pos += 256) {
      int i = pos / HALO, j = pos - i * HALO;
      int gh = refl(h0 - 1 + i, Hh);
      int gw = refl(w0 - 1 + j, Ww);
      const float* src = predb + (size_t)rpd * Hh * Ww + gh * Ww + gw;
      float v[L_];
      float m = -1e30f;
#pragma unroll
      for (int l = 0; l < L_; ++l) { v[l] = src[(size_t)l * S_SP]; m = fmaxf(m, v[l]); }
      float s = 0.f;
#pragma unroll
      for (int l = 0; l < L_; ++l) { v[l] = __expf(v[l] - m); s += v[l]; }
      float inv = 1.f / s;
#pragma unroll
      for (int l = 0; l < L_; ++l) v[l] = fmaxf(v[l] * inv, CLAMP_MIN);
      float4* dst = (float4*)&sps[pos][0];
      dst[0] = make_float4(v[0], v[1], v[2], v[3]);
      dst[1] = make_float4(v[4], v[5], v[6], v[7]);
    }
    __syncthreads();
    // ---- 3x3 2D sums for this plane (all 8 labels) ----
#pragma unroll
    for (int l = 0; l < L_; ++l) s2n[l] = 0.f;
#pragma unroll
    for (int di = 0; di < 3; ++di) {
#pragma unroll
      for (int dj = 0; dj < 3; ++dj) {
        const float4* q = (const float4*)&sps[(hl + di) * HALO + (wl + dj)][0];
        float4 a = q[0], c4 = q[1];
        s2n[0] += a.x;  s2n[1] += a.y;  s2n[2] += a.z;  s2n[3] += a.w;
        s2n[4] += c4.x; s2n[5] += c4.y; s2n[6] += c4.z; s2n[7] += c4.w;
        if (di == 1 && dj == 1) {
          ctrn[0] = a.x;  ctrn[1] = a.y;  ctrn[2] = a.z;  ctrn[3] = a.w;
          ctrn[4] = c4.x; ctrn[5] = c4.y; ctrn[6] = c4.z; ctrn[7] = c4.w;
        }
      }
    }
    // ---- output plane d = pd-1 ----
    if (pp >= 1) {
      int d = pd - 1;
      size_t off0 = (size_t)b * L_ * S_SP + (size_t)d * Hh * Ww + (h0 + hl) * Ww + (w0 + wl);
#pragma unroll
      for (int l = 0; l < L_; ++l) {
        float sum27 = s2m[l] + s2c[l] + s2n[l];
        float bt = fabsf(27.f * ctrc[l] - sum27);
        float bw = 0.5f / (bt + 0.5f);
        size_t off = off0 + (size_t)l * S_SP;
        float p = pred[off];
        float t = tgt[off];
        atop[l] += t * p * bw;
        abot[l] += (t + p) * bw;
      }
    }
#pragma unroll
    for (int l = 0; l < L_; ++l) { s2m[l] = s2c[l]; s2c[l] = s2n[l]; ctrc[l] = ctrn[l]; }
  }

  // ---- block reduction: 8 labels x (top,bot) ----
#pragma unroll
  for (int l = 0; l < L_; ++l) {
#pragma unroll
    for (int o = 32; o > 0; o >>= 1) {
      atop[l] += __shfl_down(atop[l], o, 64);
      abot[l] += __shfl_down(abot[l], o, 64);
    }
  }
  int lane = tid & 63, wv = tid >> 6;
  if (lane == 0) {
#pragma unroll
    for (int l = 0; l < L_; ++l) { red[wv][l * 2] = atop[l]; red[wv][l * 2 + 1] = abot[l]; }
  }
  __syncthreads();
  if (tid < 16) {
    float v = red[0][tid] + red[1][tid] + red[2][tid] + red[3][tid];
    partial[blk * 16 + tid] = v;   // [block][l*2 + (0=top,1=bot)]
  }
}

__global__ void finalize_kernel(const float* __restrict__ partial, float* __restrict__ out) {
  __shared__ float rr[16];
  int t = threadIdx.x;          // 256 threads: 16 pairs x 16 workers
  int p = t >> 4, k = t & 15;
  int b = p >> 3, l = p & 7;
  float top = 0.f, bot = 0.f;
  for (int m = 0; m < BLK_PER_B / 16; ++m) {     // 32 blocks each
    int blk = b * BLK_PER_B + k * (BLK_PER_B / 16) + m;
    top += partial[blk * 16 + l * 2];
    bot += partial[blk * 16 + l * 2 + 1];
  }
#pragma unroll
  for (int o = 8; o > 0; o >>= 1) {
    top += __shfl_down(top, o, 16);
    bot += __shfl_down(bot, o, 16);
  }
  if (k == 0) rr[p] = 2.f * top / fmaxf(bot, EPS);
  __syncthreads();
  if (t == 0) {
    float s = 0.f;
#pragma unroll
    for (int i = 0; i < 16; ++i) s += rr[i];
    out[0] = -s / 16.f;
  }
}

extern "C" void kernel_launch(void* const* d_in, const int* in_sizes, int n_in,
                              void* d_out, int out_size, void* d_ws, size_t ws_size,
                              hipStream_t stream) {
  const float* pred = (const float*)d_in[0];
  const float* tgt  = (const float*)d_in[1];
  float* partial = (float*)d_ws;   // NBLK*16 floats = 64 KB

  fused_kernel<<<NBLK, 256, 0, stream>>>(pred, tgt, partial);
  finalize_kernel<<<1, 256, 0, stream>>>(partial, (float*)d_out);
}